// Round 3
// baseline (388.229 us; speedup 1.0000x reference)
//
#include <hip/hip_runtime.h>

#define NNODE 50000
#define NEDGE 800000

typedef __attribute__((ext_vector_type(8))) short bf16x8;
typedef __attribute__((ext_vector_type(4))) float f32x4;

// workspace byte offsets
#define WB_QCB   0          // 64*64 bf16   qc + all folded biases (natural cols)
#define WB_WRTB  8192       // 64*64 bf16   (Wr@W1r)^T [n][k], natural k
#define WB_W2TB  16384      // 128*64 bf16  W2^T [n][perm(k)]  K-PERMUTED
#define WB_WEH   33024      // 64*64 fp32   We@W1h
#define WB_WET   49408      // 64*64 fp32   We@W1t
#define WB_NHB   65792      // 50000*64 bf16 (natural cols)
#define WB_NTB   6465792    // 50000*64 bf16

__device__ inline ushort f2b(float x) {           // fp32 -> bf16 RNE
    uint u = __float_as_uint(x);
    return (ushort)((u + 0x7fffu + ((u >> 16) & 1u)) >> 16);
}
__device__ inline uint pack2(float lo, float hi) {
    return (uint)f2b(lo) | ((uint)f2b(hi) << 16);
}
__device__ inline float bLo(uint u) { return __uint_as_float(u << 16); }
__device__ inline float bHi(uint u) { return __uint_as_float(u & 0xffff0000u); }

union B8U { uint4 u; bf16x8 b; };

__device__ inline void stage64(float* dst, const float* __restrict__ src, int t) {
    #pragma unroll
    for (int i = 0; i < 4; ++i) {
        int f = t + i * 256;
        *(float4*)&dst[f * 4] = *(const float4*)&src[f * 4];
    }
}

__device__ inline void gemm64(const float* sA, const float* sB, int t, float acc[4][4]) {
    const int r0 = (t >> 4) * 4, c0 = (t & 15) * 4;
    #pragma unroll
    for (int j = 0; j < 4; ++j)
        #pragma unroll
        for (int i = 0; i < 4; ++i) acc[j][i] = 0.f;
    #pragma unroll 4
    for (int k = 0; k < 64; ++k) {
        float4 b = *(const float4*)&sB[k * 64 + c0];
        float bv[4] = {b.x, b.y, b.z, b.w};
        #pragma unroll
        for (int j = 0; j < 4; ++j) {
            float a = sA[(r0 + j) * 64 + k];
            #pragma unroll
            for (int i = 0; i < 4; ++i) acc[j][i] = fmaf(a, bv[i], acc[j][i]);
        }
    }
}

__global__ __launch_bounds__(256)
void prep_small(const float* __restrict__ Q,
                const float* __restrict__ Wq, const float* __restrict__ bq,
                const float* __restrict__ We, const float* __restrict__ be,
                const float* __restrict__ Wr, const float* __restrict__ br,
                const float* __restrict__ W1, const float* __restrict__ b1,
                const float* __restrict__ W2, char* __restrict__ wsb)
{
    __shared__ float sA[4096], sB[4096], sC[4096], sBias[64];
    const int t = threadIdx.x;
    const int bid = blockIdx.x;
    const int r0 = (t >> 4) * 4, c0 = (t & 15) * 4;

    if (bid == 0) {
        stage64(sA, Wq, t); stage64(sB, W1, t);
        __syncthreads();
        float acc[4][4];
        gemm64(sA, sB, t, acc);
        #pragma unroll
        for (int j = 0; j < 4; ++j)
            *(float4*)&sC[(r0 + j) * 64 + c0] = make_float4(acc[j][0], acc[j][1], acc[j][2], acc[j][3]);
        if (t < 64) {
            float s = b1[t];
            for (int k = 0; k < 64; ++k) {
                s = fmaf(bq[k], W1[k * 64 + t], s);
                s = fmaf(be[k], W1[(64 + k) * 64 + t] + W1[(192 + k) * 64 + t], s);
                s = fmaf(br[k], W1[(128 + k) * 64 + t], s);
            }
            sBias[t] = s;
        }
        __syncthreads();
        stage64(sA, Q, t);
        __syncthreads();
        gemm64(sA, sC, t, acc);
        ushort* qcb = (ushort*)(wsb + WB_QCB);
        #pragma unroll
        for (int j = 0; j < 4; ++j) {
            ushort4 p;
            p.x = f2b(acc[j][0] + sBias[c0 + 0]);
            p.y = f2b(acc[j][1] + sBias[c0 + 1]);
            p.z = f2b(acc[j][2] + sBias[c0 + 2]);
            p.w = f2b(acc[j][3] + sBias[c0 + 3]);
            *(ushort4*)&qcb[(r0 + j) * 64 + c0] = p;
        }
    } else if (bid == 1 || bid == 2) {
        const float* w1seg = W1 + (bid == 1 ? 64 * 64 : 192 * 64);
        float* dst = (float*)(wsb + (bid == 1 ? WB_WEH : WB_WET));
        stage64(sA, We, t); stage64(sB, w1seg, t);
        __syncthreads();
        float acc[4][4];
        gemm64(sA, sB, t, acc);
        #pragma unroll
        for (int j = 0; j < 4; ++j)
            *(float4*)&dst[(r0 + j) * 64 + c0] = make_float4(acc[j][0], acc[j][1], acc[j][2], acc[j][3]);
    } else if (bid == 3) {
        stage64(sA, Wr, t); stage64(sB, W1 + 128 * 64, t);
        __syncthreads();
        float acc[4][4];
        gemm64(sA, sB, t, acc);
        ushort* wrtb = (ushort*)(wsb + WB_WRTB);
        #pragma unroll
        for (int j = 0; j < 4; ++j)
            #pragma unroll
            for (int i = 0; i < 4; ++i)
                wrtb[(c0 + i) * 64 + (r0 + j)] = f2b(acc[j][i]);
    } else {
        // W2^T bf16, K-permuted: stored col p(k) = (k&15)*4 + (k>>4)
        ushort* w2tb = (ushort*)(wsb + WB_W2TB);
        #pragma unroll
        for (int i = 0; i < 32; ++i) {
            int f = t + i * 256;           // f < 8192
            int k = f >> 7, n = f & 127;
            w2tb[n * 64 + ((k & 15) * 4 + (k >> 4))] = f2b(W2[f]);
        }
    }
}

__global__ __launch_bounds__(256)
void prep_nodes(const float* __restrict__ Xn, const char* __restrict__ wsb_c,
                char* __restrict__ wsb)
{
    __shared__ float sXT[64 * 68];
    __shared__ float sWeh[4096], sWet[4096];
    const int t = threadIdx.x;
    const int nbase = blockIdx.x * 64;
    const float* Weh = (const float*)(wsb_c + WB_WEH);
    const float* Wet = (const float*)(wsb_c + WB_WET);
    ushort* nhb = (ushort*)(wsb + WB_NHB);
    ushort* ntb = (ushort*)(wsb + WB_NTB);

    #pragma unroll
    for (int i = 0; i < 4; ++i) {
        int f = t + i * 256;
        int n = f >> 4, s4 = (f & 15) * 4;
        int gn = nbase + n;
        float4 v = make_float4(0.f, 0.f, 0.f, 0.f);
        if (gn < NNODE) v = *(const float4*)&Xn[gn * 64 + s4];
        sXT[(s4 + 0) * 68 + n] = v.x;
        sXT[(s4 + 1) * 68 + n] = v.y;
        sXT[(s4 + 2) * 68 + n] = v.z;
        sXT[(s4 + 3) * 68 + n] = v.w;
    }
    #pragma unroll
    for (int i = 0; i < 4; ++i) {
        int f = t + i * 256;
        *(float4*)&sWeh[f * 4] = *(const float4*)&Weh[f * 4];
        *(float4*)&sWet[f * 4] = *(const float4*)&Wet[f * 4];
    }
    __syncthreads();

    const int er = (t >> 4) * 4, cc = (t & 15) * 4;
    float ah[4][4], at[4][4];
    #pragma unroll
    for (int j = 0; j < 4; ++j)
        #pragma unroll
        for (int i = 0; i < 4; ++i) { ah[j][i] = 0.f; at[j][i] = 0.f; }
    #pragma unroll 4
    for (int k = 0; k < 64; ++k) {
        float4 a  = *(const float4*)&sXT[k * 68 + er];
        float4 bh = *(const float4*)&sWeh[k * 64 + cc];
        float4 bt = *(const float4*)&sWet[k * 64 + cc];
        float av[4] = {a.x, a.y, a.z, a.w};
        #pragma unroll
        for (int j = 0; j < 4; ++j) {
            ah[j][0] = fmaf(av[j], bh.x, ah[j][0]); ah[j][1] = fmaf(av[j], bh.y, ah[j][1]);
            ah[j][2] = fmaf(av[j], bh.z, ah[j][2]); ah[j][3] = fmaf(av[j], bh.w, ah[j][3]);
            at[j][0] = fmaf(av[j], bt.x, at[j][0]); at[j][1] = fmaf(av[j], bt.y, at[j][1]);
            at[j][2] = fmaf(av[j], bt.z, at[j][2]); at[j][3] = fmaf(av[j], bt.w, at[j][3]);
        }
    }
    #pragma unroll
    for (int j = 0; j < 4; ++j) {
        int n = nbase + er + j;
        if (n < NNODE) {
            ushort4 ph, pt;
            ph.x = f2b(ah[j][0]); ph.y = f2b(ah[j][1]); ph.z = f2b(ah[j][2]); ph.w = f2b(ah[j][3]);
            pt.x = f2b(at[j][0]); pt.y = f2b(at[j][1]); pt.z = f2b(at[j][2]); pt.w = f2b(at[j][3]);
            *(ushort4*)&nhb[n * 64 + cc] = ph;
            *(ushort4*)&ntb[n * 64 + cc] = pt;
        }
    }
}

__global__ __launch_bounds__(256, 4)
void edge_kernel(const float* __restrict__ Xe,
                 const int* __restrict__ EI,
                 const int* __restrict__ NB,
                 const float* __restrict__ b2,
                 const float* __restrict__ Wh,
                 const float* __restrict__ bh,
                 const char* __restrict__ wsb,
                 float* __restrict__ out)
{
    __shared__ ushort sG[64 * 72];     // gathered additive term, bf16, K-permuted cols
    __shared__ ushort sH[64 * 72];     // H1 bf16, K-permuted cols
    __shared__ ushort sW2[128 * 72];   // W2^T bf16 [n][perm k]
    __shared__ float  sB2s[128], sWhs[128];

    const int t = threadIdx.x;
    const int ebase = blockIdx.x * 64;
    const int l = t & 63, w = t >> 6;
    const int m = l & 15, qq = l >> 4, q8 = qq * 8;

    const ushort* qcb  = (const ushort*)(wsb + WB_QCB);
    const ushort* wrtb = (const ushort*)(wsb + WB_WRTB);
    const ushort* w2tb = (const ushort*)(wsb + WB_W2TB);
    const ushort* nhb  = (const ushort*)(wsb + WB_NHB);
    const ushort* ntb  = (const ushort*)(wsb + WB_NTB);

    // ---- gather chain (wave-local: this thread serves edge eg, quarter qg) ----
    const int eg = w * 16 + (l >> 2);
    const int qg = l & 3;
    int hd = EI[ebase + eg];
    int tl = EI[NEDGE + ebase + eg];
    int qi = NB[hd];

    // ---- X: each lane loads exactly its A-fragment slice (row w*16+m) ----
    const float* xrow = &Xe[(size_t)(ebase + w * 16 + m) * 64];
    float4 x0 = *(const float4*)&xrow[q8];
    float4 x1 = *(const float4*)&xrow[q8 + 4];
    float4 x2 = *(const float4*)&xrow[32 + q8];
    float4 x3 = *(const float4*)&xrow[32 + q8 + 4];

    // ---- Wr' B-fragments straight from global (L2-hot, 8 KB table) ----
    B8U wrB[4][2];
    #pragma unroll
    for (int nt = 0; nt < 4; ++nt) {
        const ushort* row = &wrtb[(nt * 16 + m) * 64];
        wrB[nt][0].u = *(const uint4*)&row[q8];
        wrB[nt][1].u = *(const uint4*)&row[32 + q8];
    }

    // ---- stage W2^T to LDS (only shared data needing the barrier) ----
    #pragma unroll
    for (int i = 0; i < 4; ++i) {
        int f = t + i * 256;
        *(uint4*)&sW2[(f >> 3) * 72 + (f & 7) * 8] = *(const uint4*)&w2tb[f * 8];
    }
    if (t < 128) { sB2s[t] = b2[t]; sWhs[t] = Wh[t]; }
    float bh0 = bh[0];

    // ---- gather rows, sum, write sG in permuted order (wave-local rows) ----
    {
        float s[16];
        #pragma unroll
        for (int a = 0; a < 4; ++a) {
            int coff = a * 16 + qg * 4;
            uint2 gq = *(const uint2*)&qcb[qi * 64 + coff];
            uint2 gh = *(const uint2*)&nhb[(size_t)hd * 64 + coff];
            uint2 gt = *(const uint2*)&ntb[(size_t)tl * 64 + coff];
            s[a]      = bLo(gq.x) + bLo(gh.x) + bLo(gt.x);
            s[4 + a]  = bHi(gq.x) + bHi(gh.x) + bHi(gt.x);
            s[8 + a]  = bLo(gq.y) + bLo(gh.y) + bLo(gt.y);
            s[12 + a] = bHi(gq.y) + bHi(gh.y) + bHi(gt.y);
        }
        uint pk[8];
        #pragma unroll
        for (int wd = 0; wd < 8; ++wd) pk[wd] = pack2(s[2 * wd], s[2 * wd + 1]);
        *(uint4*)&sG[eg * 72 + qg * 16]     = make_uint4(pk[0], pk[1], pk[2], pk[3]);
        *(uint4*)&sG[eg * 72 + qg * 16 + 8] = make_uint4(pk[4], pk[5], pk[6], pk[7]);
    }

    // ---- pack X A-fragments (registers only) ----
    B8U a0, a1;
    a0.u = make_uint4(pack2(x0.x, x0.y), pack2(x0.z, x0.w),
                      pack2(x1.x, x1.y), pack2(x1.z, x1.w));
    a1.u = make_uint4(pack2(x2.x, x2.y), pack2(x2.z, x2.w),
                      pack2(x3.x, x3.y), pack2(x3.z, x3.w));

    __syncthreads();   // sW2 / biases visible; everything else is wave-local

    // ---- h1 = X @ Wr'  (MFMA, C-layout: col = nt*16+m, row = qq*4+r) ----
    f32x4 acc1[4];
    #pragma unroll
    for (int nt = 0; nt < 4; ++nt) {
        f32x4 c = {0.f, 0.f, 0.f, 0.f};
        c = __builtin_amdgcn_mfma_f32_16x16x32_bf16(a0.b, wrB[nt][0].b, c, 0, 0, 0);
        c = __builtin_amdgcn_mfma_f32_16x16x32_bf16(a1.b, wrB[nt][1].b, c, 0, 0, 0);
        acc1[nt] = c;
    }

    // ---- epilogue: + gather, relu, write H1 (vector b64 ops, perm cols) ----
    #pragma unroll
    for (int r = 0; r < 4; ++r) {
        int e = w * 16 + qq * 4 + r;
        uint2 gg = *(const uint2*)&sG[e * 72 + m * 4];
        uint lo = pack2(fmaxf(acc1[0][r] + bLo(gg.x), 0.f),
                        fmaxf(acc1[1][r] + bHi(gg.x), 0.f));
        uint hi = pack2(fmaxf(acc1[2][r] + bLo(gg.y), 0.f),
                        fmaxf(acc1[3][r] + bHi(gg.y), 0.f));
        *(uint2*)&sH[e * 72 + m * 4] = make_uint2(lo, hi);
    }

    // ---- h2 = relu(H1@W2 + b2); logit = h2@Wh + bh ----
    bf16x8 A0 = *(const bf16x8*)&sH[(w * 16 + m) * 72 + q8];
    bf16x8 A1 = *(const bf16x8*)&sH[(w * 16 + m) * 72 + 32 + q8];
    float part[4] = {0.f, 0.f, 0.f, 0.f};
    #pragma unroll
    for (int nt = 0; nt < 8; ++nt) {
        bf16x8 B0 = *(const bf16x8*)&sW2[(nt * 16 + m) * 72 + q8];
        bf16x8 B1 = *(const bf16x8*)&sW2[(nt * 16 + m) * 72 + 32 + q8];
        f32x4 c = {0.f, 0.f, 0.f, 0.f};
        c = __builtin_amdgcn_mfma_f32_16x16x32_bf16(A0, B0, c, 0, 0, 0);
        c = __builtin_amdgcn_mfma_f32_16x16x32_bf16(A1, B1, c, 0, 0, 0);
        int col = nt * 16 + m;
        float b2v = sB2s[col], whv = sWhs[col];
        #pragma unroll
        for (int r = 0; r < 4; ++r)
            part[r] = fmaf(fmaxf(c[r] + b2v, 0.f), whv, part[r]);
    }
    #pragma unroll
    for (int md = 1; md < 16; md <<= 1) {
        part[0] += __shfl_xor(part[0], md, 64);
        part[1] += __shfl_xor(part[1], md, 64);
        part[2] += __shfl_xor(part[2], md, 64);
        part[3] += __shfl_xor(part[3], md, 64);
    }
    if (m == 0) {
        float4 o;
        o.x = 1.f / (1.f + __expf(-(part[0] + bh0)));
        o.y = 1.f / (1.f + __expf(-(part[1] + bh0)));
        o.z = 1.f / (1.f + __expf(-(part[2] + bh0)));
        o.w = 1.f / (1.f + __expf(-(part[3] + bh0)));
        *(float4*)&out[ebase + w * 16 + qq * 4] = o;
    }
}

extern "C" void kernel_launch(void* const* d_in, const int* in_sizes, int n_in,
                              void* d_out, int out_size, void* d_ws, size_t ws_size,
                              hipStream_t stream)
{
    const float* Q   = (const float*)d_in[0];
    const float* Xn  = (const float*)d_in[1];
    const float* Xe  = (const float*)d_in[2];
    const int*   EI  = (const int*)d_in[3];
    const int*   NB  = (const int*)d_in[4];
    const float* Wq  = (const float*)d_in[5];
    const float* bq  = (const float*)d_in[6];
    const float* We  = (const float*)d_in[7];
    const float* be  = (const float*)d_in[8];
    const float* Wr  = (const float*)d_in[9];
    const float* br  = (const float*)d_in[10];
    const float* W1  = (const float*)d_in[11];
    const float* b1  = (const float*)d_in[12];
    const float* W2  = (const float*)d_in[13];
    const float* b2  = (const float*)d_in[14];
    const float* Wh  = (const float*)d_in[15];
    const float* bh  = (const float*)d_in[16];
    float* out = (float*)d_out;
    char*  wsb = (char*)d_ws;

    prep_small<<<5, 256, 0, stream>>>(Q, Wq, bq, We, be, Wr, br, W1, b1, W2, wsb);
    prep_nodes<<<(NNODE + 63) / 64, 256, 0, stream>>>(Xn, wsb, wsb);
    edge_kernel<<<NEDGE / 64, 256, 0, stream>>>(Xe, EI, NB, b2, Wh, bh, wsb, out);
}